// Round 2
// baseline (1477.581 us; speedup 1.0000x reference)
//
#include <hip/hip_runtime.h>
#include <stdint.h>

// ---------------------------------------------------------------------------
// PointNet-style graph autoencoder, MI355X (gfx950).
//
// Dtype-agnostic: a detect kernel classifies the float tensors (fp32 vs bf16)
// and edge_index (int64 vs int32); converters canonicalize into workspace
// (bf16 tensors, int32 indices). Pipeline:
//   Gs = H @ wA_top + pos @ wA_pos + bA            (node GEMM, fp32 out)
//   Q  = pos @ wA_pos                              (node, bf16)
//   per edge e: m = relu(Gs[src] - Q[dst])  -> z = m @ wB + bB   (edge MFMA GEMM)
//   agg[dst] = max(agg[dst], z)  via atomicMax on monotone-uint-encoded f32,
//   init enc(0.0) folds the post-agg ReLU + empty-node 0.
// Decoder: two node GEMMs; final epilogue writes fp32 or bf16 per flag.
// ---------------------------------------------------------------------------

using bf16x8 = __attribute__((ext_vector_type(8))) short;
using f32x4  = __attribute__((ext_vector_type(4))) float;

__device__ __forceinline__ float b2f(uint32_t v16) {          // bf16 bits -> f32
    return __uint_as_float(v16 << 16);
}
__device__ __forceinline__ uint16_t f2b(float f) {            // f32 -> bf16 (RNE)
    uint32_t u = __float_as_uint(f);
    u += 0x7fffu + ((u >> 16) & 1u);
    return (uint16_t)(u >> 16);
}
// monotone float<->uint mapping for atomicMax-based segment_max
__device__ __forceinline__ uint32_t encf(float f) {
    uint32_t u = __float_as_uint(f);
    return (u & 0x80000000u) ? ~u : (u | 0x80000000u);
}
__device__ __forceinline__ float decf(uint32_t k) {
    uint32_t u = (k & 0x80000000u) ? (k & 0x7fffffffu) : ~k;
    return __uint_as_float(u);
}

// ---------------------------------------------------------------------------
// Dtype detection. flags[0]=1 if float tensors are fp32 (else bf16),
// flags[1]=1 if edge_index is int64 (else int32).
// fp32 N(0,1) values have exponent field in ~[117,129]; a bf16-pair
// reinterpreted as fp32 has exponent in {0..3, 234..255} -> perfect split.
// ---------------------------------------------------------------------------
__global__ void detect_fmt(const uint32_t* __restrict__ x,
                           const uint32_t* __restrict__ ei,
                           uint32_t* __restrict__ flags) {
    if (threadIdx.x == 0 && blockIdx.x == 0) {
        int plaus = 0;
        for (int i = 0; i < 64; i++) {
            uint32_t v = x[i];
            uint32_t e = (v >> 23) & 0xffu;
            if (v == 0u || (e >= 96u && e <= 150u)) plaus++;
        }
        flags[0] = (plaus >= 48) ? 1u : 0u;
        int zeros = 0;
        for (int i = 0; i < 16; i++)
            if (ei[2 * i + 1] == 0u) zeros++;
        flags[1] = (zeros == 16) ? 1u : 0u;
    }
}

// big float tensor -> canonical bf16 (4 elems/thread)
__global__ __launch_bounds__(256) void convert_big(
        const void* __restrict__ src, uint16_t* __restrict__ dst, int n,
        const uint32_t* __restrict__ flags) {
    bool isf32 = flags[0] != 0u;
    int i = (blockIdx.x * 256 + threadIdx.x) * 4;
    if (i + 3 < n) {
        if (isf32) {
            float4 v = ((const float4*)src)[i >> 2];
            uint16_t o0 = f2b(v.x), o1 = f2b(v.y), o2 = f2b(v.z), o3 = f2b(v.w);
            uint2 o = {(uint32_t)o0 | ((uint32_t)o1 << 16),
                       (uint32_t)o2 | ((uint32_t)o3 << 16)};
            ((uint2*)dst)[i >> 2] = o;
        } else {
            ((uint2*)dst)[i >> 2] = ((const uint2*)src)[i >> 2];
        }
    } else {
        for (int j = i; j < n; j++)
            dst[j] = isf32 ? f2b(((const float*)src)[j]) : ((const uint16_t*)src)[j];
    }
}

struct ConvArgs {
    const void* src[13];
    uint32_t dstOff[13];
    uint32_t n[13];
};

// batched small float tensors -> canonical bf16 arena
__global__ __launch_bounds__(256) void convert_small(
        ConvArgs a, uint16_t* __restrict__ dstBase, const uint32_t* __restrict__ flags) {
    bool isf32 = flags[0] != 0u;
    int t = blockIdx.y;
    int i = blockIdx.x * 256 + threadIdx.x;
    if (i >= (int)a.n[t]) return;
    uint16_t* d = dstBase + a.dstOff[t];
    d[i] = isf32 ? f2b(((const float*)a.src[t])[i]) : ((const uint16_t*)a.src[t])[i];
}

// edge_index -> canonical int32 (handles int64 input)
__global__ __launch_bounds__(256) void convert_ei(
        const int* __restrict__ src, int* __restrict__ dst, int n2,
        const uint32_t* __restrict__ flags) {
    bool i64 = flags[1] != 0u;
    int i = blockIdx.x * 256 + threadIdx.x;
    if (i < n2) dst[i] = i64 ? src[2 * i] : src[i];
}

// ---------------------------------------------------------------------------
// Transpose+chunk-tile the 6 [256x256] B-matrices into WT:
//   WT[w][ (k>>6)*16384 + n*64 + (k&63) ] = W[k*256 + n]
// ---------------------------------------------------------------------------
__global__ __launch_bounds__(256) void transpose_w(
        const uint16_t* s0, const uint16_t* s1, const uint16_t* s2,
        const uint16_t* s3, const uint16_t* s4, const uint16_t* s5,
        uint16_t* dst) {
    const uint16_t* srcs[6] = {s0, s1, s2, s3, s4, s5};
    const uint16_t* src = srcs[blockIdx.y];
    uint16_t* d = dst + (size_t)blockIdx.y * 65536;
    int k = blockIdx.x;          // grid.x = 256
    int n = threadIdx.x;
    d[(k >> 6) * 16384 + n * 64 + (k & 63)] = src[k * 256 + n];
}

// Q[i][c] = sum_d pos[i][d] * wpos[d][c]   (wpos = wA rows 256..258)
__global__ __launch_bounds__(256) void pos_proj(
        const uint16_t* pos, const uint16_t* wpos, uint16_t* Q, int N) {
    int c = threadIdx.x;
    float w0 = b2f(wpos[c]), w1 = b2f(wpos[256 + c]), w2 = b2f(wpos[512 + c]);
    int base = blockIdx.x * 8;
#pragma unroll
    for (int n = 0; n < 8; n++) {
        int i = base + n;
        if (i >= N) break;
        float p0 = b2f(pos[i * 3 + 0]);
        float p1 = b2f(pos[i * 3 + 1]);
        float p2 = b2f(pos[i * 3 + 2]);
        Q[(size_t)i * 256 + c] = f2b(p0 * w0 + p1 * w1 + p2 * w2);
    }
}

__global__ __launch_bounds__(256) void init_agg(uint32_t* agg, int n4) {
    int i = blockIdx.x * 256 + threadIdx.x;
    if (i < n4) {
        uint4 v = {0x80000000u, 0x80000000u, 0x80000000u, 0x80000000u};  // enc(+0)
        ((uint4*)agg)[i] = v;
    }
}

__global__ __launch_bounds__(256) void finalize_h(const uint32_t* agg, uint16_t* h, int n4) {
    int i = blockIdx.x * 256 + threadIdx.x;
    if (i < n4) {
        uint4 a = ((const uint4*)agg)[i];
        uint32_t p0 = (uint32_t)f2b(decf(a.x)) | ((uint32_t)f2b(decf(a.y)) << 16);
        uint32_t p1 = (uint32_t)f2b(decf(a.z)) | ((uint32_t)f2b(decf(a.w)) << 16);
        uint2 o = {p0, p1};
        ((uint2*)h)[i] = o;
    }
}

// ---------------------------------------------------------------------------
// Node GEMM: C[M,256] = A[M,256] @ W[256,256] (+bias) (+Q) (relu)
// Tile: 64 rows x 256 cols, 256 threads / 4 waves; wave w owns cols [w*64,+64).
// MODE 0: out f32, +bias +Q (Gs build).  MODE 1: out bf16, +bias, relu.
// MODE 2: out per-flag dtype, +bias (final decoder stage).
// ---------------------------------------------------------------------------
template <int MODE>
__global__ __launch_bounds__(256) void gemm_node(
        const uint16_t* __restrict__ A, const uint16_t* __restrict__ BT,
        const uint16_t* __restrict__ bias, const uint16_t* __restrict__ Qadd,
        void* __restrict__ out, int M, const uint32_t* __restrict__ flags) {
    __shared__ __align__(16) uint16_t Al[64 * 72];
    __shared__ __align__(16) uint16_t Bl[256 * 72];
    int tid = threadIdx.x;
    int tileM = blockIdx.x;
    int wave = tid >> 6, lane = tid & 63, lrow = lane & 15, quad = lane >> 4;
    f32x4 acc[4][4] = {};

    for (int kc = 0; kc < 256; kc += 64) {
        {   // stage A chunk: 64 rows x 64 k, 16 shorts / thread
            int row = tid >> 2, kq = (tid & 3) * 16;
            int rg = tileM * 64 + row;
            uint4 v0 = {0, 0, 0, 0}, v1 = {0, 0, 0, 0};
            if (rg < M) {
                const uint4* p = (const uint4*)(A + (size_t)rg * 256 + kc + kq);
                v0 = p[0]; v1 = p[1];
            }
            uint4* q = (uint4*)&Al[row * 72 + kq];
            q[0] = v0; q[1] = v1;
        }
        {   // stage B chunk: contiguous 128 B / thread
            const uint4* p = (const uint4*)(BT + (kc >> 6) * 16384 + tid * 64);
            uint4* q = (uint4*)&Bl[tid * 72];
#pragma unroll
            for (int j = 0; j < 8; j++) q[j] = p[j];
        }
        __syncthreads();
#pragma unroll
        for (int ks = 0; ks < 64; ks += 32) {
            bf16x8 af[4], bfr[4];
#pragma unroll
            for (int r = 0; r < 4; r++)
                af[r] = *(const bf16x8*)&Al[(r * 16 + lrow) * 72 + ks + quad * 8];
#pragma unroll
            for (int c = 0; c < 4; c++)
                bfr[c] = *(const bf16x8*)&Bl[(wave * 64 + c * 16 + lrow) * 72 + ks + quad * 8];
#pragma unroll
            for (int r = 0; r < 4; r++)
#pragma unroll
                for (int c = 0; c < 4; c++)
                    acc[r][c] = __builtin_amdgcn_mfma_f32_16x16x32_bf16(af[r], bfr[c], acc[r][c], 0, 0, 0);
        }
        __syncthreads();
    }

    bool of32 = false;
    if (MODE == 2) of32 = flags[0] != 0u;

#pragma unroll
    for (int c = 0; c < 4; c++) {
        int col = wave * 64 + c * 16 + lrow;
        float bv = b2f(bias[col]);
#pragma unroll
        for (int r = 0; r < 4; r++) {
#pragma unroll
            for (int i = 0; i < 4; i++) {
                int rg = tileM * 64 + r * 16 + quad * 4 + i;
                if (rg >= M) continue;
                float v = acc[r][c][i] + bv;
                if (MODE == 0) {
                    v += b2f(Qadd[(size_t)rg * 256 + col]);
                    ((float*)out)[(size_t)rg * 256 + col] = v;
                } else if (MODE == 1) {
                    v = fmaxf(v, 0.f);
                    ((uint16_t*)out)[(size_t)rg * 256 + col] = f2b(v);
                } else {
                    if (of32) ((float*)out)[(size_t)rg * 256 + col] = v;
                    else      ((uint16_t*)out)[(size_t)rg * 256 + col] = f2b(v);
                }
            }
        }
    }
}

// ---------------------------------------------------------------------------
// Edge kernel: tile = 64 edges x 256 cols. A rows built on the fly:
//   m[e] = relu(Gs[src[e]] (f32) - Q[dst[e]] (bf16)) -> bf16
// then z = m @ wB + bB, atomicMax into agg[dst].
// ---------------------------------------------------------------------------
__global__ __launch_bounds__(256) void edge_gemm_agg(
        const float* __restrict__ Gs, const uint16_t* __restrict__ Qb,
        const uint16_t* __restrict__ BT, const uint16_t* __restrict__ bias,
        const int* __restrict__ ei, int E, uint32_t* __restrict__ agg) {
    __shared__ __align__(16) uint16_t Al[64 * 72];
    __shared__ __align__(16) uint16_t Bl[256 * 72];
    __shared__ int ssrc[64], sdst[64];
    int tid = threadIdx.x;
    int ebase = blockIdx.x * 64;
    int evalid = (E - ebase < 64) ? (E - ebase) : 64;
    if (tid < 64) {
        int s = 0, d = 0;
        if (tid < evalid) {
            s = ei[ebase + tid];
            d = ei[E + ebase + tid];
        }
        ssrc[tid] = s;
        sdst[tid] = d;
    }
    __syncthreads();
    int wave = tid >> 6, lane = tid & 63, lrow = lane & 15, quad = lane >> 4;
    f32x4 acc[4][4] = {};

    for (int kc = 0; kc < 256; kc += 64) {
        {   // stage A: gather + relu(sub) + bf16 pack, 16 elems / thread
            int row = tid >> 2, kq = (tid & 3) * 16;
            int s = ssrc[row], dd = sdst[row];
            const float4* gp = (const float4*)(Gs + (size_t)s * 256 + kc + kq);
            const uint4*  qp = (const uint4*)(Qb + (size_t)dd * 256 + kc + kq);
            float4 g0 = gp[0], g1 = gp[1], g2 = gp[2], g3 = gp[3];
            uint4 q0 = qp[0], q1 = qp[1];
            float gv[16] = {g0.x, g0.y, g0.z, g0.w, g1.x, g1.y, g1.z, g1.w,
                            g2.x, g2.y, g2.z, g2.w, g3.x, g3.y, g3.z, g3.w};
            uint32_t qs[8] = {q0.x, q0.y, q0.z, q0.w, q1.x, q1.y, q1.z, q1.w};
            uint32_t mw[8];
#pragma unroll
            for (int j = 0; j < 8; j++) {
                float a = fmaxf(gv[2 * j]     - b2f(qs[j] & 0xffffu), 0.f);
                float b = fmaxf(gv[2 * j + 1] - b2f(qs[j] >> 16), 0.f);
                mw[j] = (uint32_t)f2b(a) | ((uint32_t)f2b(b) << 16);
            }
            uint4* wp = (uint4*)&Al[row * 72 + kq];
            uint4 w0 = {mw[0], mw[1], mw[2], mw[3]};
            uint4 w1 = {mw[4], mw[5], mw[6], mw[7]};
            wp[0] = w0; wp[1] = w1;
        }
        {   // stage B
            const uint4* p = (const uint4*)(BT + (kc >> 6) * 16384 + tid * 64);
            uint4* q = (uint4*)&Bl[tid * 72];
#pragma unroll
            for (int j = 0; j < 8; j++) q[j] = p[j];
        }
        __syncthreads();
#pragma unroll
        for (int ks = 0; ks < 64; ks += 32) {
            bf16x8 af[4], bfr[4];
#pragma unroll
            for (int r = 0; r < 4; r++)
                af[r] = *(const bf16x8*)&Al[(r * 16 + lrow) * 72 + ks + quad * 8];
#pragma unroll
            for (int c = 0; c < 4; c++)
                bfr[c] = *(const bf16x8*)&Bl[(wave * 64 + c * 16 + lrow) * 72 + ks + quad * 8];
#pragma unroll
            for (int r = 0; r < 4; r++)
#pragma unroll
                for (int c = 0; c < 4; c++)
                    acc[r][c] = __builtin_amdgcn_mfma_f32_16x16x32_bf16(af[r], bfr[c], acc[r][c], 0, 0, 0);
        }
        __syncthreads();
    }

    // epilogue: z = acc + bias, atomic segment-max at dst
    float bv[4];
#pragma unroll
    for (int c = 0; c < 4; c++) bv[c] = b2f(bias[wave * 64 + c * 16 + lrow]);
#pragma unroll
    for (int r = 0; r < 4; r++) {
#pragma unroll
        for (int i = 0; i < 4; i++) {
            int erow = r * 16 + quad * 4 + i;
            if (erow >= evalid) continue;
            int d = sdst[erow];
            uint32_t* base = agg + (size_t)d * 256 + wave * 64;
#pragma unroll
            for (int c = 0; c < 4; c++) {
                int col = c * 16 + lrow;
                float v = acc[r][c][i] + bv[c];
                atomicMax(base + col, encf(v));
            }
        }
    }
}

// ---------------------------------------------------------------------------
extern "C" void kernel_launch(void* const* d_in, const int* in_sizes, int n_in,
                              void* d_out, int out_size, void* d_ws, size_t ws_size,
                              hipStream_t stream) {
    const void* x_raw   = d_in[0];
    const void* pos_raw = d_in[1];
    const int*  ei_raw  = (const int*)d_in[2];

    int N = in_sizes[0] / 256;     // 50000
    int E = in_sizes[2] / 2;       // 800000

    // ---- workspace layout (256B-aligned chunks) ----
    char* ws = (char*)d_ws;
    size_t off = 0;
    auto alloc = [&](size_t bytes) { void* p = ws + off; off += (bytes + 255) & ~(size_t)255; return p; };

    uint32_t* flags = (uint32_t*)alloc(256);
    uint16_t* WT    = (uint16_t*)alloc(6 * 65536 * sizeof(uint16_t));          // 768 KB
    // canonical small-tensor arena: pos + 12 weight/bias tensors
    const uint32_t POS_OFF = 0;
    const uint32_t W1A_OFF = POS_OFF + (uint32_t)(N * 3);     // 66304 elems
    const uint32_t W2A_OFF = W1A_OFF + 66304;
    const uint32_t W1B_OFF = W2A_OFF + 66304;
    const uint32_t W2B_OFF = W1B_OFF + 65536;
    const uint32_t WD1_OFF = W2B_OFF + 65536;
    const uint32_t WD2_OFF = WD1_OFF + 65536;
    const uint32_t B1A_OFF = WD2_OFF + 65536;
    const uint32_t B1B_OFF = B1A_OFF + 256;
    const uint32_t B2A_OFF = B1B_OFF + 256;
    const uint32_t B2B_OFF = B2A_OFF + 256;
    const uint32_t BD1_OFF = B2B_OFF + 256;
    const uint32_t BD2_OFF = BD1_OFF + 256;
    const uint32_t ARENA_ELEMS = BD2_OFF + 256;
    uint16_t* arena = (uint16_t*)alloc((size_t)ARENA_ELEMS * 2);
    int*      ei32  = (int*)alloc((size_t)2 * E * 4);                          // 6.4 MB
    uint16_t* Qb    = (uint16_t*)alloc((size_t)N * 256 * 2);                   // 25.6 MB
    float*    Gs    = (float*)alloc((size_t)N * 256 * 4);                      // 51.2 MB
    uint32_t* agg   = (uint32_t*)alloc((size_t)N * 256 * 4);                   // 51.2 MB
    uint16_t* xb    = (uint16_t*)alloc((size_t)N * 256 * 2);                   // 25.6 MB
    uint16_t* h     = xb;               // alias: xb dead after layer-1 node GEMM
    uint16_t* d1    = (uint16_t*)Gs;    // alias: Gs dead after layer-2 edge pass

    uint16_t* posb = arena + POS_OFF;
    uint16_t* w1a = arena + W1A_OFF, * w2a = arena + W2A_OFF;
    uint16_t* w1b = arena + W1B_OFF, * w2b = arena + W2B_OFF;
    uint16_t* wd1 = arena + WD1_OFF, * wd2 = arena + WD2_OFF;
    uint16_t* b1a = arena + B1A_OFF, * b1b = arena + B1B_OFF;
    uint16_t* b2a = arena + B2A_OFF, * b2b = arena + B2B_OFF;
    uint16_t* bd1 = arena + BD1_OFF, * bd2 = arena + BD2_OFF;

    int n4      = N * 64;                 // (N*256)/4
    int nbElem  = (n4 + 255) / 256;
    int nbNode  = (N + 63) / 64;
    int nbEdge  = (E + 63) / 64;
    int nbPos   = (N + 7) / 8;

    // ---- detection + canonicalization ----
    detect_fmt<<<1, 64, 0, stream>>>((const uint32_t*)x_raw, (const uint32_t*)ei_raw, flags);
    convert_big<<<(N * 256 / 4 + 255) / 256, 256, 0, stream>>>(x_raw, xb, N * 256, flags);

    ConvArgs ca;
    ca.src[0] = pos_raw;  ca.dstOff[0] = POS_OFF; ca.n[0] = (uint32_t)(N * 3);
    ca.src[1] = d_in[3];  ca.dstOff[1] = W1A_OFF; ca.n[1] = 66304;
    ca.src[2] = d_in[7];  ca.dstOff[2] = W2A_OFF; ca.n[2] = 66304;
    ca.src[3] = d_in[5];  ca.dstOff[3] = W1B_OFF; ca.n[3] = 65536;
    ca.src[4] = d_in[9];  ca.dstOff[4] = W2B_OFF; ca.n[4] = 65536;
    ca.src[5] = d_in[11]; ca.dstOff[5] = WD1_OFF; ca.n[5] = 65536;
    ca.src[6] = d_in[13]; ca.dstOff[6] = WD2_OFF; ca.n[6] = 65536;
    ca.src[7] = d_in[4];  ca.dstOff[7] = B1A_OFF; ca.n[7] = 256;
    ca.src[8] = d_in[6];  ca.dstOff[8] = B1B_OFF; ca.n[8] = 256;
    ca.src[9] = d_in[8];  ca.dstOff[9] = B2A_OFF; ca.n[9] = 256;
    ca.src[10] = d_in[10]; ca.dstOff[10] = B2B_OFF; ca.n[10] = 256;
    ca.src[11] = d_in[12]; ca.dstOff[11] = BD1_OFF; ca.n[11] = 256;
    ca.src[12] = d_in[14]; ca.dstOff[12] = BD2_OFF; ca.n[12] = 256;
    {
        uint32_t maxn = (uint32_t)(N * 3);
        dim3 g((maxn + 255) / 256, 13);
        convert_small<<<g, 256, 0, stream>>>(ca, arena, flags);
    }
    convert_ei<<<(2 * E + 255) / 256, 256, 0, stream>>>(ei_raw, ei32, 2 * E, flags);

    transpose_w<<<dim3(256, 6), 256, 0, stream>>>(w1a, w1b, w2a, w2b, wd1, wd2, WT);

    // ---- layer 1 ----
    pos_proj<<<nbPos, 256, 0, stream>>>(posb, w1a + 65536, Qb, N);
    gemm_node<0><<<nbNode, 256, 0, stream>>>(xb, WT + 0 * 65536, b1a, Qb, Gs, N, flags);
    init_agg<<<nbElem, 256, 0, stream>>>(agg, n4);
    edge_gemm_agg<<<nbEdge, 256, 0, stream>>>(Gs, Qb, WT + 1 * 65536, b1b, ei32, E, agg);
    finalize_h<<<nbElem, 256, 0, stream>>>(agg, h, n4);

    // ---- layer 2 ----
    pos_proj<<<nbPos, 256, 0, stream>>>(posb, w2a + 65536, Qb, N);
    gemm_node<0><<<nbNode, 256, 0, stream>>>(h, WT + 2 * 65536, b2a, Qb, Gs, N, flags);
    init_agg<<<nbElem, 256, 0, stream>>>(agg, n4);
    edge_gemm_agg<<<nbEdge, 256, 0, stream>>>(Gs, Qb, WT + 3 * 65536, b2b, ei32, E, agg);
    finalize_h<<<nbElem, 256, 0, stream>>>(agg, h, n4);

    // ---- decoder ----
    gemm_node<1><<<nbNode, 256, 0, stream>>>(h, WT + 4 * 65536, bd1, nullptr, d1, N, flags);
    gemm_node<2><<<nbNode, 256, 0, stream>>>(d1, WT + 5 * 65536, bd2, nullptr, d_out, N, flags);
}

// Round 3
// 1360.970 us; speedup vs baseline: 1.0857x; 1.0857x over previous
//
#include <hip/hip_runtime.h>
#include <stdint.h>

// ---------------------------------------------------------------------------
// PointNet-style graph autoencoder, MI355X (gfx950).
//
// R3: edges are counting-sorted by dst once; the edge kernel pre-reduces the
// segment-max over same-dst runs inside each 64-edge tile (z parked in LDS,
// overlaying the dead staging buffers) and emits ONE coalesced atomic per
// (run, col) instead of one per (edge, col): ~12x fewer device-scope atomics.
//
// Pipeline per layer:
//   Gs = H @ wA_top + pos @ wA_pos + bA            (node GEMM, fp32 out)
//   Q  = pos @ wA_pos                              (node, bf16)
//   per edge e: m = relu(Gs[src] - Q[dst])  -> z = m @ wB + bB   (edge MFMA)
//   agg[dst] = max(agg[dst], z)  via atomicMax on monotone-uint-encoded f32,
//   init enc(0.0) folds the post-agg ReLU + empty-node 0.
// ---------------------------------------------------------------------------

using bf16x8 = __attribute__((ext_vector_type(8))) short;
using f32x4  = __attribute__((ext_vector_type(4))) float;

__device__ __forceinline__ float b2f(uint32_t v16) {          // bf16 bits -> f32
    return __uint_as_float(v16 << 16);
}
__device__ __forceinline__ uint16_t f2b(float f) {            // f32 -> bf16 (RNE)
    uint32_t u = __float_as_uint(f);
    u += 0x7fffu + ((u >> 16) & 1u);
    return (uint16_t)(u >> 16);
}
// monotone float<->uint mapping for atomicMax-based segment_max
__device__ __forceinline__ uint32_t encf(float f) {
    uint32_t u = __float_as_uint(f);
    return (u & 0x80000000u) ? ~u : (u | 0x80000000u);
}
__device__ __forceinline__ float decf(uint32_t k) {
    uint32_t u = (k & 0x80000000u) ? (k & 0x7fffffffu) : ~k;
    return __uint_as_float(u);
}

// ---------------------------------------------------------------------------
// Dtype detection. flags[0]=1 if float tensors are fp32 (else bf16),
// flags[1]=1 if edge_index is int64 (else int32).
// ---------------------------------------------------------------------------
__global__ void detect_fmt(const uint32_t* __restrict__ x,
                           const uint32_t* __restrict__ ei,
                           uint32_t* __restrict__ flags) {
    if (threadIdx.x == 0 && blockIdx.x == 0) {
        int plaus = 0;
        for (int i = 0; i < 64; i++) {
            uint32_t v = x[i];
            uint32_t e = (v >> 23) & 0xffu;
            if (v == 0u || (e >= 96u && e <= 150u)) plaus++;
        }
        flags[0] = (plaus >= 48) ? 1u : 0u;
        int zeros = 0;
        for (int i = 0; i < 16; i++)
            if (ei[2 * i + 1] == 0u) zeros++;
        flags[1] = (zeros == 16) ? 1u : 0u;
    }
}

// big float tensor -> canonical bf16 (4 elems/thread)
__global__ __launch_bounds__(256) void convert_big(
        const void* __restrict__ src, uint16_t* __restrict__ dst, int n,
        const uint32_t* __restrict__ flags) {
    bool isf32 = flags[0] != 0u;
    int i = (blockIdx.x * 256 + threadIdx.x) * 4;
    if (i + 3 < n) {
        if (isf32) {
            float4 v = ((const float4*)src)[i >> 2];
            uint16_t o0 = f2b(v.x), o1 = f2b(v.y), o2 = f2b(v.z), o3 = f2b(v.w);
            uint2 o = {(uint32_t)o0 | ((uint32_t)o1 << 16),
                       (uint32_t)o2 | ((uint32_t)o3 << 16)};
            ((uint2*)dst)[i >> 2] = o;
        } else {
            ((uint2*)dst)[i >> 2] = ((const uint2*)src)[i >> 2];
        }
    } else {
        for (int j = i; j < n; j++)
            dst[j] = isf32 ? f2b(((const float*)src)[j]) : ((const uint16_t*)src)[j];
    }
}

struct ConvArgs {
    const void* src[13];
    uint32_t dstOff[13];
    uint32_t n[13];
};

// batched small float tensors -> canonical bf16 arena
__global__ __launch_bounds__(256) void convert_small(
        ConvArgs a, uint16_t* __restrict__ dstBase, const uint32_t* __restrict__ flags) {
    bool isf32 = flags[0] != 0u;
    int t = blockIdx.y;
    int i = blockIdx.x * 256 + threadIdx.x;
    if (i >= (int)a.n[t]) return;
    uint16_t* d = dstBase + a.dstOff[t];
    d[i] = isf32 ? f2b(((const float*)a.src[t])[i]) : ((const uint16_t*)a.src[t])[i];
}

// ---------------------------------------------------------------------------
// Counting sort of edges by dst.
// ---------------------------------------------------------------------------
__global__ __launch_bounds__(256) void zero_i32(int* p, int n) {
    int i = blockIdx.x * 256 + threadIdx.x;
    if (i < n) p[i] = 0;
}

__global__ __launch_bounds__(256) void hist_dst(
        const int* __restrict__ ei_raw, int E, int* __restrict__ hist,
        const uint32_t* __restrict__ flags) {
    bool i64 = flags[1] != 0u;
    int e = blockIdx.x * 256 + threadIdx.x;
    if (e < E) {
        int d = i64 ? ei_raw[2 * (E + e)] : ei_raw[E + e];
        atomicAdd(&hist[d], 1);
    }
}

// single-block exclusive scan of hist[0..N) -> cursor (wave-shuffle based)
__global__ __launch_bounds__(1024) void scan_bins(
        const int* __restrict__ hist, int* __restrict__ cursor, int N) {
    __shared__ int wsum[16];
    __shared__ int carry;
    int tid = threadIdx.x, lane = tid & 63, wid = tid >> 6;
    if (tid == 0) carry = 0;
    __syncthreads();
    for (int base = 0; base < N; base += 1024) {
        int v = (base + tid < N) ? hist[base + tid] : 0;
        int x = v;
#pragma unroll
        for (int s = 1; s < 64; s <<= 1) {
            int t = __shfl_up(x, s, 64);
            if (lane >= s) x += t;
        }
        if (lane == 63) wsum[wid] = x;
        __syncthreads();
        if (wid == 0 && lane < 16) {
            int w = wsum[lane];
#pragma unroll
            for (int s = 1; s < 16; s <<= 1) {
                int t = __shfl_up(w, s, 64);
                if (lane >= s) w += t;
            }
            wsum[lane] = w;        // inclusive wave sums
        }
        __syncthreads();
        int wbase = (wid > 0) ? wsum[wid - 1] : 0;
        int excl = x - v + wbase + carry;
        if (base + tid < N) cursor[base + tid] = excl;
        __syncthreads();
        if (tid == 0) carry += wsum[15];
        __syncthreads();
    }
}

__global__ __launch_bounds__(256) void scatter_edges(
        const int* __restrict__ ei_raw, int E, int* __restrict__ cursor,
        int* __restrict__ esrc, int* __restrict__ edst,
        const uint32_t* __restrict__ flags) {
    bool i64 = flags[1] != 0u;
    int e = blockIdx.x * 256 + threadIdx.x;
    if (e < E) {
        int s = i64 ? ei_raw[2 * e] : ei_raw[e];
        int d = i64 ? ei_raw[2 * (E + e)] : ei_raw[E + e];
        int p = atomicAdd(&cursor[d], 1);
        esrc[p] = s;
        edst[p] = d;
    }
}

// ---------------------------------------------------------------------------
// Transpose+chunk-tile the 6 [256x256] B-matrices into WT:
//   WT[w][ (k>>6)*16384 + n*64 + (k&63) ] = W[k*256 + n]
// ---------------------------------------------------------------------------
__global__ __launch_bounds__(256) void transpose_w(
        const uint16_t* s0, const uint16_t* s1, const uint16_t* s2,
        const uint16_t* s3, const uint16_t* s4, const uint16_t* s5,
        uint16_t* dst) {
    const uint16_t* srcs[6] = {s0, s1, s2, s3, s4, s5};
    const uint16_t* src = srcs[blockIdx.y];
    uint16_t* d = dst + (size_t)blockIdx.y * 65536;
    int k = blockIdx.x;          // grid.x = 256
    int n = threadIdx.x;
    d[(k >> 6) * 16384 + n * 64 + (k & 63)] = src[k * 256 + n];
}

// Q[i][c] = sum_d pos[i][d] * wpos[d][c]   (wpos = wA rows 256..258)
__global__ __launch_bounds__(256) void pos_proj(
        const uint16_t* pos, const uint16_t* wpos, uint16_t* Q, int N) {
    int c = threadIdx.x;
    float w0 = b2f(wpos[c]), w1 = b2f(wpos[256 + c]), w2 = b2f(wpos[512 + c]);
    int base = blockIdx.x * 8;
#pragma unroll
    for (int n = 0; n < 8; n++) {
        int i = base + n;
        if (i >= N) break;
        float p0 = b2f(pos[i * 3 + 0]);
        float p1 = b2f(pos[i * 3 + 1]);
        float p2 = b2f(pos[i * 3 + 2]);
        Q[(size_t)i * 256 + c] = f2b(p0 * w0 + p1 * w1 + p2 * w2);
    }
}

__global__ __launch_bounds__(256) void init_agg(uint32_t* agg, int n4) {
    int i = blockIdx.x * 256 + threadIdx.x;
    if (i < n4) {
        uint4 v = {0x80000000u, 0x80000000u, 0x80000000u, 0x80000000u};  // enc(+0)
        ((uint4*)agg)[i] = v;
    }
}

__global__ __launch_bounds__(256) void finalize_h(const uint32_t* agg, uint16_t* h, int n4) {
    int i = blockIdx.x * 256 + threadIdx.x;
    if (i < n4) {
        uint4 a = ((const uint4*)agg)[i];
        uint32_t p0 = (uint32_t)f2b(decf(a.x)) | ((uint32_t)f2b(decf(a.y)) << 16);
        uint32_t p1 = (uint32_t)f2b(decf(a.z)) | ((uint32_t)f2b(decf(a.w)) << 16);
        uint2 o = {p0, p1};
        ((uint2*)h)[i] = o;
    }
}

// ---------------------------------------------------------------------------
// Node GEMM: C[M,256] = A[M,256] @ W[256,256] (+bias) (+Q) (relu)
// Tile: 64 rows x 256 cols, 256 threads / 4 waves; wave w owns cols [w*64,+64).
// MODE 0: out f32, +bias +Q (Gs build).  MODE 1: out bf16, +bias, relu.
// MODE 2: out per-flag dtype, +bias (final decoder stage).
// ---------------------------------------------------------------------------
template <int MODE>
__global__ __launch_bounds__(256) void gemm_node(
        const uint16_t* __restrict__ A, const uint16_t* __restrict__ BT,
        const uint16_t* __restrict__ bias, const uint16_t* __restrict__ Qadd,
        void* __restrict__ out, int M, const uint32_t* __restrict__ flags) {
    __shared__ __align__(16) uint16_t Al[64 * 72];
    __shared__ __align__(16) uint16_t Bl[256 * 72];
    int tid = threadIdx.x;
    int tileM = blockIdx.x;
    int wave = tid >> 6, lane = tid & 63, lrow = lane & 15, quad = lane >> 4;
    f32x4 acc[4][4] = {};

    for (int kc = 0; kc < 256; kc += 64) {
        {   // stage A chunk: 64 rows x 64 k, 16 shorts / thread
            int row = tid >> 2, kq = (tid & 3) * 16;
            int rg = tileM * 64 + row;
            uint4 v0 = {0, 0, 0, 0}, v1 = {0, 0, 0, 0};
            if (rg < M) {
                const uint4* p = (const uint4*)(A + (size_t)rg * 256 + kc + kq);
                v0 = p[0]; v1 = p[1];
            }
            uint4* q = (uint4*)&Al[row * 72 + kq];
            q[0] = v0; q[1] = v1;
        }
        {   // stage B chunk: contiguous 128 B / thread
            const uint4* p = (const uint4*)(BT + (kc >> 6) * 16384 + tid * 64);
            uint4* q = (uint4*)&Bl[tid * 72];
#pragma unroll
            for (int j = 0; j < 8; j++) q[j] = p[j];
        }
        __syncthreads();
#pragma unroll
        for (int ks = 0; ks < 64; ks += 32) {
            bf16x8 af[4], bfr[4];
#pragma unroll
            for (int r = 0; r < 4; r++)
                af[r] = *(const bf16x8*)&Al[(r * 16 + lrow) * 72 + ks + quad * 8];
#pragma unroll
            for (int c = 0; c < 4; c++)
                bfr[c] = *(const bf16x8*)&Bl[(wave * 64 + c * 16 + lrow) * 72 + ks + quad * 8];
#pragma unroll
            for (int r = 0; r < 4; r++)
#pragma unroll
                for (int c = 0; c < 4; c++)
                    acc[r][c] = __builtin_amdgcn_mfma_f32_16x16x32_bf16(af[r], bfr[c], acc[r][c], 0, 0, 0);
        }
        __syncthreads();
    }

    bool of32 = false;
    if (MODE == 2) of32 = flags[0] != 0u;

#pragma unroll
    for (int c = 0; c < 4; c++) {
        int col = wave * 64 + c * 16 + lrow;
        float bv = b2f(bias[col]);
#pragma unroll
        for (int r = 0; r < 4; r++) {
#pragma unroll
            for (int i = 0; i < 4; i++) {
                int rg = tileM * 64 + r * 16 + quad * 4 + i;
                if (rg >= M) continue;
                float v = acc[r][c][i] + bv;
                if (MODE == 0) {
                    v += b2f(Qadd[(size_t)rg * 256 + col]);
                    ((float*)out)[(size_t)rg * 256 + col] = v;
                } else if (MODE == 1) {
                    v = fmaxf(v, 0.f);
                    ((uint16_t*)out)[(size_t)rg * 256 + col] = f2b(v);
                } else {
                    if (of32) ((float*)out)[(size_t)rg * 256 + col] = v;
                    else      ((uint16_t*)out)[(size_t)rg * 256 + col] = f2b(v);
                }
            }
        }
    }
}

// ---------------------------------------------------------------------------
// Edge kernel over dst-SORTED edges: tile = 64 edges x 256 cols.
//   m = relu(Gs[src] - Q[dst]) -> bf16; z = m @ wB + bB.
// Epilogue: z (bf16, monotone RNE commutes with max) parked in LDS overlaying
// the dead staging buffers; each thread scans its column over the 64 sorted
// rows and flushes one coalesced atomicMax per same-dst run.
// ---------------------------------------------------------------------------
#define ZPAD 264
__global__ __launch_bounds__(256) void edge_gemm_agg(
        const float* __restrict__ Gs, const uint16_t* __restrict__ Qb,
        const uint16_t* __restrict__ BT, const uint16_t* __restrict__ bias,
        const int* __restrict__ esrc, const int* __restrict__ edst, int E,
        uint32_t* __restrict__ agg) {
    __shared__ __align__(16) uint16_t SM[64 * 72 + 256 * 72];   // 46080 B
    uint16_t* Al = SM;
    uint16_t* Bl = SM + 64 * 72;
    uint16_t* Zl = SM;                                          // overlay, 64*ZPAD
    __shared__ int ssrc[64], sdst[64];
    int tid = threadIdx.x;
    int ebase = blockIdx.x * 64;
    int evalid = (E - ebase < 64) ? (E - ebase) : 64;
    if (tid < 64) {
        int s = 0, d = 0;
        if (tid < evalid) {
            s = esrc[ebase + tid];
            d = edst[ebase + tid];
        }
        ssrc[tid] = s;
        sdst[tid] = d;
    }
    __syncthreads();
    int wave = tid >> 6, lane = tid & 63, lrow = lane & 15, quad = lane >> 4;
    f32x4 acc[4][4] = {};

    for (int kc = 0; kc < 256; kc += 64) {
        {   // stage A: gather + relu(sub) + bf16 pack, 16 elems / thread
            int row = tid >> 2, kq = (tid & 3) * 16;
            int s = ssrc[row], dd = sdst[row];
            const float4* gp = (const float4*)(Gs + (size_t)s * 256 + kc + kq);
            const uint4*  qp = (const uint4*)(Qb + (size_t)dd * 256 + kc + kq);
            float4 g0 = gp[0], g1 = gp[1], g2 = gp[2], g3 = gp[3];
            uint4 q0 = qp[0], q1 = qp[1];
            float gv[16] = {g0.x, g0.y, g0.z, g0.w, g1.x, g1.y, g1.z, g1.w,
                            g2.x, g2.y, g2.z, g2.w, g3.x, g3.y, g3.z, g3.w};
            uint32_t qs[8] = {q0.x, q0.y, q0.z, q0.w, q1.x, q1.y, q1.z, q1.w};
            uint32_t mw[8];
#pragma unroll
            for (int j = 0; j < 8; j++) {
                float a = fmaxf(gv[2 * j]     - b2f(qs[j] & 0xffffu), 0.f);
                float b = fmaxf(gv[2 * j + 1] - b2f(qs[j] >> 16), 0.f);
                mw[j] = (uint32_t)f2b(a) | ((uint32_t)f2b(b) << 16);
            }
            uint4* wp = (uint4*)&Al[row * 72 + kq];
            uint4 w0 = {mw[0], mw[1], mw[2], mw[3]};
            uint4 w1 = {mw[4], mw[5], mw[6], mw[7]};
            wp[0] = w0; wp[1] = w1;
        }
        {   // stage B
            const uint4* p = (const uint4*)(BT + (kc >> 6) * 16384 + tid * 64);
            uint4* q = (uint4*)&Bl[tid * 72];
#pragma unroll
            for (int j = 0; j < 8; j++) q[j] = p[j];
        }
        __syncthreads();
#pragma unroll
        for (int ks = 0; ks < 64; ks += 32) {
            bf16x8 af[4], bfr[4];
#pragma unroll
            for (int r = 0; r < 4; r++)
                af[r] = *(const bf16x8*)&Al[(r * 16 + lrow) * 72 + ks + quad * 8];
#pragma unroll
            for (int c = 0; c < 4; c++)
                bfr[c] = *(const bf16x8*)&Bl[(wave * 64 + c * 16 + lrow) * 72 + ks + quad * 8];
#pragma unroll
            for (int r = 0; r < 4; r++)
#pragma unroll
                for (int c = 0; c < 4; c++)
                    acc[r][c] = __builtin_amdgcn_mfma_f32_16x16x32_bf16(af[r], bfr[c], acc[r][c], 0, 0, 0);
        }
        __syncthreads();
    }

    // park z = acc + bias in LDS as bf16 (RNE is monotone: commutes with max)
    float bv[4];
#pragma unroll
    for (int c = 0; c < 4; c++) bv[c] = b2f(bias[wave * 64 + c * 16 + lrow]);
#pragma unroll
    for (int r = 0; r < 4; r++)
#pragma unroll
        for (int i = 0; i < 4; i++) {
            int erow = r * 16 + quad * 4 + i;
#pragma unroll
            for (int c = 0; c < 4; c++)
                Zl[erow * ZPAD + wave * 64 + c * 16 + lrow] = f2b(acc[r][c][i] + bv[c]);
        }
    __syncthreads();

    // run-max over sorted dst, one coalesced atomic per (run, col)
    int col = tid;
    float run = 0.f;
    int dprev = -1;
    for (int row = 0; row < evalid; row++) {
        int d = sdst[row];                       // block-uniform broadcast
        float v = b2f(Zl[row * ZPAD + col]);
        if (d != dprev) {
            if (dprev >= 0)
                atomicMax(agg + (size_t)dprev * 256 + col, encf(run));
            dprev = d;
            run = v;
        } else {
            run = fmaxf(run, v);
        }
    }
    if (dprev >= 0)
        atomicMax(agg + (size_t)dprev * 256 + col, encf(run));
}

// ---------------------------------------------------------------------------
extern "C" void kernel_launch(void* const* d_in, const int* in_sizes, int n_in,
                              void* d_out, int out_size, void* d_ws, size_t ws_size,
                              hipStream_t stream) {
    const void* x_raw   = d_in[0];
    const void* pos_raw = d_in[1];
    const int*  ei_raw  = (const int*)d_in[2];

    int N = in_sizes[0] / 256;     // 50000
    int E = in_sizes[2] / 2;       // 800000

    // ---- workspace layout (256B-aligned chunks) ----
    char* ws = (char*)d_ws;
    size_t off = 0;
    auto alloc = [&](size_t bytes) { void* p = ws + off; off += (bytes + 255) & ~(size_t)255; return p; };

    uint32_t* flags = (uint32_t*)alloc(256);
    uint16_t* WT    = (uint16_t*)alloc(6 * 65536 * sizeof(uint16_t));          // 768 KB
    const uint32_t POS_OFF = 0;
    const uint32_t W1A_OFF = POS_OFF + (uint32_t)(N * 3);
    const uint32_t W2A_OFF = W1A_OFF + 66304;
    const uint32_t W1B_OFF = W2A_OFF + 66304;
    const uint32_t W2B_OFF = W1B_OFF + 65536;
    const uint32_t WD1_OFF = W2B_OFF + 65536;
    const uint32_t WD2_OFF = WD1_OFF + 65536;
    const uint32_t B1A_OFF = WD2_OFF + 65536;
    const uint32_t B1B_OFF = B1A_OFF + 256;
    const uint32_t B2A_OFF = B1B_OFF + 256;
    const uint32_t B2B_OFF = B2A_OFF + 256;
    const uint32_t BD1_OFF = B2B_OFF + 256;
    const uint32_t BD2_OFF = BD1_OFF + 256;
    const uint32_t ARENA_ELEMS = BD2_OFF + 256;
    uint16_t* arena = (uint16_t*)alloc((size_t)ARENA_ELEMS * 2);
    int*      hist  = (int*)alloc((size_t)N * 4);                              // 200 KB
    int*      curs  = (int*)alloc((size_t)N * 4);                              // 200 KB
    int*      esrc  = (int*)alloc((size_t)E * 4);                              // 3.2 MB
    int*      edst  = (int*)alloc((size_t)E * 4);                              // 3.2 MB
    uint16_t* Qb    = (uint16_t*)alloc((size_t)N * 256 * 2);                   // 25.6 MB
    float*    Gs    = (float*)alloc((size_t)N * 256 * 4);                      // 51.2 MB
    uint32_t* agg   = (uint32_t*)alloc((size_t)N * 256 * 4);                   // 51.2 MB
    uint16_t* xb    = (uint16_t*)alloc((size_t)N * 256 * 2);                   // 25.6 MB
    uint16_t* h     = xb;               // alias: xb dead after layer-1 node GEMM
    uint16_t* d1    = (uint16_t*)Gs;    // alias: Gs dead after layer-2 edge pass

    uint16_t* posb = arena + POS_OFF;
    uint16_t* w1a = arena + W1A_OFF, * w2a = arena + W2A_OFF;
    uint16_t* w1b = arena + W1B_OFF, * w2b = arena + W2B_OFF;
    uint16_t* wd1 = arena + WD1_OFF, * wd2 = arena + WD2_OFF;
    uint16_t* b1a = arena + B1A_OFF, * b1b = arena + B1B_OFF;
    uint16_t* b2a = arena + B2A_OFF, * b2b = arena + B2B_OFF;
    uint16_t* bd1 = arena + BD1_OFF, * bd2 = arena + BD2_OFF;

    int n4      = N * 64;
    int nbElem  = (n4 + 255) / 256;
    int nbNode  = (N + 63) / 64;
    int nbEdge  = (E + 63) / 64;
    int nbE256  = (E + 255) / 256;
    int nbPos   = (N + 7) / 8;

    // ---- detection + canonicalization ----
    detect_fmt<<<1, 64, 0, stream>>>((const uint32_t*)x_raw, (const uint32_t*)ei_raw, flags);
    convert_big<<<(N * 256 / 4 + 255) / 256, 256, 0, stream>>>(x_raw, xb, N * 256, flags);

    ConvArgs ca;
    ca.src[0] = pos_raw;  ca.dstOff[0] = POS_OFF; ca.n[0] = (uint32_t)(N * 3);
    ca.src[1] = d_in[3];  ca.dstOff[1] = W1A_OFF; ca.n[1] = 66304;
    ca.src[2] = d_in[7];  ca.dstOff[2] = W2A_OFF; ca.n[2] = 66304;
    ca.src[3] = d_in[5];  ca.dstOff[3] = W1B_OFF; ca.n[3] = 65536;
    ca.src[4] = d_in[9];  ca.dstOff[4] = W2B_OFF; ca.n[4] = 65536;
    ca.src[5] = d_in[11]; ca.dstOff[5] = WD1_OFF; ca.n[5] = 65536;
    ca.src[6] = d_in[13]; ca.dstOff[6] = WD2_OFF; ca.n[6] = 65536;
    ca.src[7] = d_in[4];  ca.dstOff[7] = B1A_OFF; ca.n[7] = 256;
    ca.src[8] = d_in[6];  ca.dstOff[8] = B1B_OFF; ca.n[8] = 256;
    ca.src[9] = d_in[8];  ca.dstOff[9] = B2A_OFF; ca.n[9] = 256;
    ca.src[10] = d_in[10]; ca.dstOff[10] = B2B_OFF; ca.n[10] = 256;
    ca.src[11] = d_in[12]; ca.dstOff[11] = BD1_OFF; ca.n[11] = 256;
    ca.src[12] = d_in[14]; ca.dstOff[12] = BD2_OFF; ca.n[12] = 256;
    {
        uint32_t maxn = (uint32_t)(N * 3);
        dim3 g((maxn + 255) / 256, 13);
        convert_small<<<g, 256, 0, stream>>>(ca, arena, flags);
    }

    // ---- counting sort of edges by dst (once, reused by both layers) ----
    zero_i32<<<(N + 255) / 256, 256, 0, stream>>>(hist, N);
    hist_dst<<<nbE256, 256, 0, stream>>>(ei_raw, E, hist, flags);
    scan_bins<<<1, 1024, 0, stream>>>(hist, curs, N);
    scatter_edges<<<nbE256, 256, 0, stream>>>(ei_raw, E, curs, esrc, edst, flags);

    transpose_w<<<dim3(256, 6), 256, 0, stream>>>(w1a, w1b, w2a, w2b, wd1, wd2, WT);

    // ---- layer 1 ----
    pos_proj<<<nbPos, 256, 0, stream>>>(posb, w1a + 65536, Qb, N);
    gemm_node<0><<<nbNode, 256, 0, stream>>>(xb, WT + 0 * 65536, b1a, Qb, Gs, N, flags);
    init_agg<<<nbElem, 256, 0, stream>>>(agg, n4);
    edge_gemm_agg<<<nbEdge, 256, 0, stream>>>(Gs, Qb, WT + 1 * 65536, b1b, esrc, edst, E, agg);
    finalize_h<<<nbElem, 256, 0, stream>>>(agg, h, n4);

    // ---- layer 2 ----
    pos_proj<<<nbPos, 256, 0, stream>>>(posb, w2a + 65536, Qb, N);
    gemm_node<0><<<nbNode, 256, 0, stream>>>(h, WT + 2 * 65536, b2a, Qb, Gs, N, flags);
    init_agg<<<nbElem, 256, 0, stream>>>(agg, n4);
    edge_gemm_agg<<<nbEdge, 256, 0, stream>>>(Gs, Qb, WT + 3 * 65536, b2b, esrc, edst, E, agg);
    finalize_h<<<nbElem, 256, 0, stream>>>(agg, h, n4);

    // ---- decoder ----
    gemm_node<1><<<nbNode, 256, 0, stream>>>(h, WT + 4 * 65536, bd1, nullptr, d1, N, flags);
    gemm_node<2><<<nbNode, 256, 0, stream>>>(d1, WT + 5 * 65536, bd2, nullptr, d_out, N, flags);
}

// Round 4
// 923.223 us; speedup vs baseline: 1.6005x; 1.4742x over previous
//
#include <hip/hip_runtime.h>
#include <stdint.h>

// ---------------------------------------------------------------------------
// PointNet-style graph autoencoder, MI355X (gfx950).
//
// R4: edge kernel restructured for occupancy + VALU:
//   - BK=32 K-chunks: staging LDS 25.6 KB, total (Z overlay) 34.8 KB -> 4
//     blocks/CU (was 3 at 46.6 KB).
//   - v_cvt_pk_bf16_f32 (guarded) for the relu(Gs-Q) -> bf16 pack.
//   - Z parked column-major; run-max scan reads 4 rows per ds_read_b64 with
//     a ballot-precomputed run-boundary mask (uniform branches).
// Edges counting-sorted by dst once; one atomicMax per (run, col).
// ---------------------------------------------------------------------------

using bf16x8 = __attribute__((ext_vector_type(8))) short;
using f32x4  = __attribute__((ext_vector_type(4))) float;

#define AB_STRIDE 40      // shorts per staged row (32 k + 8 pad) -> 16B aligned
#define ZSTRIDE   68      // shorts per Z column (64 rows + 4 pad)

__device__ __forceinline__ float b2f(uint32_t v16) {          // bf16 bits -> f32
    return __uint_as_float(v16 << 16);
}
__device__ __forceinline__ uint16_t f2b(float f) {            // f32 -> bf16 (RNE)
    uint32_t u = __float_as_uint(f);
    u += 0x7fffu + ((u >> 16) & 1u);
    return (uint16_t)(u >> 16);
}
#if __has_builtin(__builtin_amdgcn_cvt_pk_bf16_f32)
__device__ __forceinline__ uint32_t pack2bf(float lo, float hi) {
    auto r = __builtin_amdgcn_cvt_pk_bf16_f32(lo, hi);   // D.lo=cvt(S0), D.hi=cvt(S1), RNE
    uint32_t u; __builtin_memcpy(&u, &r, 4); return u;
}
#else
__device__ __forceinline__ uint32_t pack2bf(float lo, float hi) {
    return (uint32_t)f2b(lo) | ((uint32_t)f2b(hi) << 16);
}
#endif
// monotone float<->uint mapping for atomicMax-based segment_max
__device__ __forceinline__ uint32_t encf(float f) {
    uint32_t u = __float_as_uint(f);
    return (u & 0x80000000u) ? ~u : (u | 0x80000000u);
}
__device__ __forceinline__ float decf(uint32_t k) {
    uint32_t u = (k & 0x80000000u) ? (k & 0x7fffffffu) : ~k;
    return __uint_as_float(u);
}

// ---------------------------------------------------------------------------
// Dtype detection. flags[0]=1 if float tensors are fp32 (else bf16),
// flags[1]=1 if edge_index is int64 (else int32).
// ---------------------------------------------------------------------------
__global__ void detect_fmt(const uint32_t* __restrict__ x,
                           const uint32_t* __restrict__ ei,
                           uint32_t* __restrict__ flags) {
    if (threadIdx.x == 0 && blockIdx.x == 0) {
        int plaus = 0;
        for (int i = 0; i < 64; i++) {
            uint32_t v = x[i];
            uint32_t e = (v >> 23) & 0xffu;
            if (v == 0u || (e >= 96u && e <= 150u)) plaus++;
        }
        flags[0] = (plaus >= 48) ? 1u : 0u;
        int zeros = 0;
        for (int i = 0; i < 16; i++)
            if (ei[2 * i + 1] == 0u) zeros++;
        flags[1] = (zeros == 16) ? 1u : 0u;
    }
}

// big float tensor -> canonical bf16 (4 elems/thread)
__global__ __launch_bounds__(256) void convert_big(
        const void* __restrict__ src, uint16_t* __restrict__ dst, int n,
        const uint32_t* __restrict__ flags) {
    bool isf32 = flags[0] != 0u;
    int i = (blockIdx.x * 256 + threadIdx.x) * 4;
    if (i + 3 < n) {
        if (isf32) {
            float4 v = ((const float4*)src)[i >> 2];
            uint2 o = {pack2bf(v.x, v.y), pack2bf(v.z, v.w)};
            ((uint2*)dst)[i >> 2] = o;
        } else {
            ((uint2*)dst)[i >> 2] = ((const uint2*)src)[i >> 2];
        }
    } else {
        for (int j = i; j < n; j++)
            dst[j] = isf32 ? f2b(((const float*)src)[j]) : ((const uint16_t*)src)[j];
    }
}

struct ConvArgs {
    const void* src[13];
    uint32_t dstOff[13];
    uint32_t n[13];
};

// batched small float tensors -> canonical bf16 arena
__global__ __launch_bounds__(256) void convert_small(
        ConvArgs a, uint16_t* __restrict__ dstBase, const uint32_t* __restrict__ flags) {
    bool isf32 = flags[0] != 0u;
    int t = blockIdx.y;
    int i = blockIdx.x * 256 + threadIdx.x;
    if (i >= (int)a.n[t]) return;
    uint16_t* d = dstBase + a.dstOff[t];
    d[i] = isf32 ? f2b(((const float*)a.src[t])[i]) : ((const uint16_t*)a.src[t])[i];
}

// ---------------------------------------------------------------------------
// Counting sort of edges by dst.
// ---------------------------------------------------------------------------
__global__ __launch_bounds__(256) void zero_i32(int* p, int n) {
    int i = blockIdx.x * 256 + threadIdx.x;
    if (i < n) p[i] = 0;
}

__global__ __launch_bounds__(256) void hist_dst(
        const int* __restrict__ ei_raw, int E, int* __restrict__ hist,
        const uint32_t* __restrict__ flags) {
    bool i64 = flags[1] != 0u;
    int e = blockIdx.x * 256 + threadIdx.x;
    if (e < E) {
        int d = i64 ? ei_raw[2 * (E + e)] : ei_raw[E + e];
        atomicAdd(&hist[d], 1);
    }
}

// single-block exclusive scan of hist[0..N) -> cursor (wave-shuffle based)
__global__ __launch_bounds__(1024) void scan_bins(
        const int* __restrict__ hist, int* __restrict__ cursor, int N) {
    __shared__ int wsum[16];
    __shared__ int carry;
    int tid = threadIdx.x, lane = tid & 63, wid = tid >> 6;
    if (tid == 0) carry = 0;
    __syncthreads();
    for (int base = 0; base < N; base += 1024) {
        int v = (base + tid < N) ? hist[base + tid] : 0;
        int x = v;
#pragma unroll
        for (int s = 1; s < 64; s <<= 1) {
            int t = __shfl_up(x, s, 64);
            if (lane >= s) x += t;
        }
        if (lane == 63) wsum[wid] = x;
        __syncthreads();
        if (wid == 0 && lane < 16) {
            int w = wsum[lane];
#pragma unroll
            for (int s = 1; s < 16; s <<= 1) {
                int t = __shfl_up(w, s, 64);
                if (lane >= s) w += t;
            }
            wsum[lane] = w;        // inclusive wave sums
        }
        __syncthreads();
        int wbase = (wid > 0) ? wsum[wid - 1] : 0;
        int excl = x - v + wbase + carry;
        if (base + tid < N) cursor[base + tid] = excl;
        __syncthreads();
        if (tid == 0) carry += wsum[15];
        __syncthreads();
    }
}

__global__ __launch_bounds__(256) void scatter_edges(
        const int* __restrict__ ei_raw, int E, int* __restrict__ cursor,
        int* __restrict__ esrc, int* __restrict__ edst,
        const uint32_t* __restrict__ flags) {
    bool i64 = flags[1] != 0u;
    int e = blockIdx.x * 256 + threadIdx.x;
    if (e < E) {
        int s = i64 ? ei_raw[2 * e] : ei_raw[e];
        int d = i64 ? ei_raw[2 * (E + e)] : ei_raw[E + e];
        int p = atomicAdd(&cursor[d], 1);
        esrc[p] = s;
        edst[p] = d;
    }
}

// ---------------------------------------------------------------------------
// Transpose+chunk-tile the 6 [256x256] B-matrices into WT (32-k chunks):
//   WT[w][ (k>>5)*8192 + n*32 + (k&31) ] = W[k*256 + n]
// ---------------------------------------------------------------------------
__global__ __launch_bounds__(256) void transpose_w(
        const uint16_t* s0, const uint16_t* s1, const uint16_t* s2,
        const uint16_t* s3, const uint16_t* s4, const uint16_t* s5,
        uint16_t* dst) {
    const uint16_t* srcs[6] = {s0, s1, s2, s3, s4, s5};
    const uint16_t* src = srcs[blockIdx.y];
    uint16_t* d = dst + (size_t)blockIdx.y * 65536;
    int k = blockIdx.x;          // grid.x = 256
    int n = threadIdx.x;
    d[(k >> 5) * 8192 + n * 32 + (k & 31)] = src[k * 256 + n];
}

// Q[i][c] = sum_d pos[i][d] * wpos[d][c]   (wpos = wA rows 256..258)
__global__ __launch_bounds__(256) void pos_proj(
        const uint16_t* pos, const uint16_t* wpos, uint16_t* Q, int N) {
    int c = threadIdx.x;
    float w0 = b2f(wpos[c]), w1 = b2f(wpos[256 + c]), w2 = b2f(wpos[512 + c]);
    int base = blockIdx.x * 8;
#pragma unroll
    for (int n = 0; n < 8; n++) {
        int i = base + n;
        if (i >= N) break;
        float p0 = b2f(pos[i * 3 + 0]);
        float p1 = b2f(pos[i * 3 + 1]);
        float p2 = b2f(pos[i * 3 + 2]);
        Q[(size_t)i * 256 + c] = f2b(p0 * w0 + p1 * w1 + p2 * w2);
    }
}

__global__ __launch_bounds__(256) void init_agg(uint32_t* agg, int n4) {
    int i = blockIdx.x * 256 + threadIdx.x;
    if (i < n4) {
        uint4 v = {0x80000000u, 0x80000000u, 0x80000000u, 0x80000000u};  // enc(+0)
        ((uint4*)agg)[i] = v;
    }
}

__global__ __launch_bounds__(256) void finalize_h(const uint32_t* agg, uint16_t* h, int n4) {
    int i = blockIdx.x * 256 + threadIdx.x;
    if (i < n4) {
        uint4 a = ((const uint4*)agg)[i];
        uint2 o = {pack2bf(decf(a.x), decf(a.y)), pack2bf(decf(a.z), decf(a.w))};
        ((uint2*)h)[i] = o;
    }
}

// ---------------------------------------------------------------------------
// Node GEMM (BK=32): C[M,256] = A[M,256] @ W[256,256] (+bias) (+Q) (relu)
// Tile: 64 rows x 256 cols, 256 threads / 4 waves; wave w owns cols [w*64,+64).
// MODE 0: out f32, +bias +Q (Gs build).  MODE 1: out bf16, +bias, relu.
// MODE 2: out per-flag dtype, +bias (final decoder stage).
// ---------------------------------------------------------------------------
template <int MODE>
__global__ __launch_bounds__(256) void gemm_node(
        const uint16_t* __restrict__ A, const uint16_t* __restrict__ BT,
        const uint16_t* __restrict__ bias, const uint16_t* __restrict__ Qadd,
        void* __restrict__ out, int M, const uint32_t* __restrict__ flags) {
    __shared__ __align__(16) uint16_t Al[64 * AB_STRIDE];
    __shared__ __align__(16) uint16_t Bl[256 * AB_STRIDE];
    int tid = threadIdx.x;
    int tileM = blockIdx.x;
    int wave = tid >> 6, lane = tid & 63, lrow = lane & 15, quad = lane >> 4;
    f32x4 acc[4][4] = {};

    int row = tid >> 2, kq = (tid & 3) * 8;
    for (int kc = 0; kc < 256; kc += 32) {
        {   // stage A chunk: 64 rows x 32 k, 8 shorts / thread
            int rg = tileM * 64 + row;
            uint4 v = {0, 0, 0, 0};
            if (rg < M) v = *(const uint4*)(A + (size_t)rg * 256 + kc + kq);
            *(uint4*)&Al[row * AB_STRIDE + kq] = v;
        }
        {   // stage B chunk: 64 B / thread
            const uint4* p = (const uint4*)(BT + (kc >> 5) * 8192 + tid * 32);
#pragma unroll
            for (int j = 0; j < 4; j++) *(uint4*)&Bl[tid * AB_STRIDE + j * 8] = p[j];
        }
        __syncthreads();
        bf16x8 af[4], bfr[4];
#pragma unroll
        for (int r = 0; r < 4; r++)
            af[r] = *(const bf16x8*)&Al[(r * 16 + lrow) * AB_STRIDE + quad * 8];
#pragma unroll
        for (int c = 0; c < 4; c++)
            bfr[c] = *(const bf16x8*)&Bl[(wave * 64 + c * 16 + lrow) * AB_STRIDE + quad * 8];
#pragma unroll
        for (int r = 0; r < 4; r++)
#pragma unroll
            for (int c = 0; c < 4; c++)
                acc[r][c] = __builtin_amdgcn_mfma_f32_16x16x32_bf16(af[r], bfr[c], acc[r][c], 0, 0, 0);
        __syncthreads();
    }

    bool of32 = false;
    if (MODE == 2) of32 = flags[0] != 0u;

#pragma unroll
    for (int c = 0; c < 4; c++) {
        int col = wave * 64 + c * 16 + lrow;
        float bv = b2f(bias[col]);
#pragma unroll
        for (int r = 0; r < 4; r++) {
#pragma unroll
            for (int i = 0; i < 4; i++) {
                int rg = tileM * 64 + r * 16 + quad * 4 + i;
                if (rg >= M) continue;
                float v = acc[r][c][i] + bv;
                if (MODE == 0) {
                    v += b2f(Qadd[(size_t)rg * 256 + col]);
                    ((float*)out)[(size_t)rg * 256 + col] = v;
                } else if (MODE == 1) {
                    v = fmaxf(v, 0.f);
                    ((uint16_t*)out)[(size_t)rg * 256 + col] = f2b(v);
                } else {
                    if (of32) ((float*)out)[(size_t)rg * 256 + col] = v;
                    else      ((uint16_t*)out)[(size_t)rg * 256 + col] = f2b(v);
                }
            }
        }
    }
}

// ---------------------------------------------------------------------------
// Edge kernel over dst-SORTED edges (BK=32): tile = 64 edges x 256 cols.
//   m = relu(Gs[src] - Q[dst]) -> bf16; z = m @ wB + bB.
// Epilogue: z parked COLUMN-MAJOR in LDS (overlay on dead staging); run-max
// scan reads 4 rows per ds_read_b64, run boundaries from a ballot mask;
// one coalesced atomicMax per (run, col).
// ---------------------------------------------------------------------------
__global__ __launch_bounds__(256, 4) void edge_gemm_agg(
        const float* __restrict__ Gs, const uint16_t* __restrict__ Qb,
        const uint16_t* __restrict__ BT, const uint16_t* __restrict__ bias,
        const int* __restrict__ esrc, const int* __restrict__ edst, int E,
        uint32_t* __restrict__ agg) {
    __shared__ __align__(16) uint16_t SM[256 * ZSTRIDE];     // 34816 B (>= staging 25600)
    uint16_t* Al = SM;                       // 64 x AB_STRIDE
    uint16_t* Bl = SM + 64 * AB_STRIDE;      // 256 x AB_STRIDE
    uint16_t* Zl = SM;                       // overlay: col-major 256 x ZSTRIDE
    __shared__ int ssrc[64], sdst[64];
    __shared__ uint64_t smask;
    int tid = threadIdx.x;
    int ebase = blockIdx.x * 64;
    int evalid = (E - ebase < 64) ? (E - ebase) : 64;
    if (tid < 64) {
        int s = 0, d = 0;
        if (tid < evalid) {
            s = esrc[ebase + tid];
            d = edst[ebase + tid];
        }
        ssrc[tid] = s;
        sdst[tid] = d;
    }
    __syncthreads();
    int wave = tid >> 6, lane = tid & 63, lrow = lane & 15, quad = lane >> 4;
    f32x4 acc[4][4] = {};

    int row = tid >> 2, kq = (tid & 3) * 8;
    int s = ssrc[row], dd = sdst[row];
    const float* gbase = Gs + (size_t)s * 256 + kq;
    const uint16_t* qbase = Qb + (size_t)dd * 256 + kq;

    for (int kc = 0; kc < 256; kc += 32) {
        {   // stage A: gather + relu(sub) + pk-bf16 pack, 8 elems / thread
            const float4* gp = (const float4*)(gbase + kc);
            float4 g0 = gp[0], g1 = gp[1];
            uint4 q = *(const uint4*)(qbase + kc);
            uint32_t m0 = pack2bf(fmaxf(g0.x - b2f(q.x & 0xffffu), 0.f),
                                  fmaxf(g0.y - b2f(q.x >> 16), 0.f));
            uint32_t m1 = pack2bf(fmaxf(g0.z - b2f(q.y & 0xffffu), 0.f),
                                  fmaxf(g0.w - b2f(q.y >> 16), 0.f));
            uint32_t m2 = pack2bf(fmaxf(g1.x - b2f(q.z & 0xffffu), 0.f),
                                  fmaxf(g1.y - b2f(q.z >> 16), 0.f));
            uint32_t m3 = pack2bf(fmaxf(g1.z - b2f(q.w & 0xffffu), 0.f),
                                  fmaxf(g1.w - b2f(q.w >> 16), 0.f));
            uint4 wv = {m0, m1, m2, m3};
            *(uint4*)&Al[row * AB_STRIDE + kq] = wv;
        }
        {   // stage B: 64 B / thread, contiguous
            const uint4* p = (const uint4*)(BT + (kc >> 5) * 8192 + tid * 32);
#pragma unroll
            for (int j = 0; j < 4; j++) *(uint4*)&Bl[tid * AB_STRIDE + j * 8] = p[j];
        }
        __syncthreads();
        bf16x8 af[4], bfr[4];
#pragma unroll
        for (int r = 0; r < 4; r++)
            af[r] = *(const bf16x8*)&Al[(r * 16 + lrow) * AB_STRIDE + quad * 8];
#pragma unroll
        for (int c = 0; c < 4; c++)
            bfr[c] = *(const bf16x8*)&Bl[(wave * 64 + c * 16 + lrow) * AB_STRIDE + quad * 8];
#pragma unroll
        for (int r = 0; r < 4; r++)
#pragma unroll
            for (int c = 0; c < 4; c++)
                acc[r][c] = __builtin_amdgcn_mfma_f32_16x16x32_bf16(af[r], bfr[c], acc[r][c], 0, 0, 0);
        __syncthreads();
    }

    // park z = acc + bias in LDS col-major as bf16 (RNE monotone: commutes w/ max)
    float bv[4];
#pragma unroll
    for (int c = 0; c < 4; c++) bv[c] = b2f(bias[wave * 64 + c * 16 + lrow]);
#pragma unroll
    for (int c = 0; c < 4; c++) {
        int col = wave * 64 + c * 16 + lrow;
#pragma unroll
        for (int r = 0; r < 4; r++) {
            uint2 z4 = {pack2bf(acc[r][c][0] + bv[c], acc[r][c][1] + bv[c]),
                        pack2bf(acc[r][c][2] + bv[c], acc[r][c][3] + bv[c])};
            *(uint2*)&Zl[col * ZSTRIDE + r * 16 + quad * 4] = z4;
        }
    }
    // run-boundary mask (uniform): bit r set where sdst[r] != sdst[r-1]
    if (wave == 0) {
        int d0 = sdst[lane];
        int dp = (lane > 0) ? sdst[lane - 1] : -1;
        uint64_t m = __ballot(d0 != dp);
        if (lane == 0) smask = m;
    }
    __syncthreads();

    // run-max over sorted dst, one coalesced atomic per (run, col)
    uint64_t mask = smask;
    int col = tid;
    const uint16_t* zc = &Zl[col * ZSTRIDE];
    float run = 0.f;
#pragma unroll 4
    for (int g = 0; g < 16; g++) {
        int rbase = g * 4;
        if (rbase >= evalid) break;
        uint2 z4 = *(const uint2*)&zc[rbase];
        float vv[4] = {b2f(z4.x & 0xffffu), b2f(z4.x >> 16),
                       b2f(z4.y & 0xffffu), b2f(z4.y >> 16)};
#pragma unroll
        for (int i = 0; i < 4; i++) {
            int r = rbase + i;
            if (r >= evalid) break;
            if (r == 0) {
                run = vv[0];
            } else if ((mask >> r) & 1ull) {
                int dp = sdst[r - 1];
                atomicMax(agg + (size_t)dp * 256 + col, encf(run));
                run = vv[i];
            } else {
                run = fmaxf(run, vv[i]);
            }
        }
    }
    if (evalid > 0)
        atomicMax(agg + (size_t)sdst[evalid - 1] * 256 + col, encf(run));
}

// ---------------------------------------------------------------------------
extern "C" void kernel_launch(void* const* d_in, const int* in_sizes, int n_in,
                              void* d_out, int out_size, void* d_ws, size_t ws_size,
                              hipStream_t stream) {
    const void* x_raw   = d_in[0];
    const void* pos_raw = d_in[1];
    const int*  ei_raw  = (const int*)d_in[2];

    int N = in_sizes[0] / 256;     // 50000
    int E = in_sizes[2] / 2;       // 800000

    // ---- workspace layout (256B-aligned chunks) ----
    char* ws = (char*)d_ws;
    size_t off = 0;
    auto alloc = [&](size_t bytes) { void* p = ws + off; off += (bytes + 255) & ~(size_t)255; return p; };

    uint32_t* flags = (uint32_t*)alloc(256);
    uint16_t* WT    = (uint16_t*)alloc(6 * 65536 * sizeof(uint16_t));          // 768 KB
    const uint32_t POS_OFF = 0;
    const uint32_t W1A_OFF = POS_OFF + (uint32_t)(N * 3);
    const uint32_t W2A_OFF = W1A_OFF + 66304;
    const uint32_t W1B_OFF = W2A_OFF + 66304;
    const uint32_t W2B_OFF = W1B_OFF + 65536;
    const uint32_t WD1_OFF = W2B_OFF + 65536;
    const uint32_t WD2_OFF = WD1_OFF + 65536;
    const uint32_t B1A_OFF = WD2_OFF + 65536;
    const uint32_t B1B_OFF = B1A_OFF + 256;
    const uint32_t B2A_OFF = B1B_OFF + 256;
    const uint32_t B2B_OFF = B2A_OFF + 256;
    const uint32_t BD1_OFF = B2B_OFF + 256;
    const uint32_t BD2_OFF = BD1_OFF + 256;
    const uint32_t ARENA_ELEMS = BD2_OFF + 256;
    uint16_t* arena = (uint16_t*)alloc((size_t)ARENA_ELEMS * 2);
    int*      hist  = (int*)alloc((size_t)N * 4);
    int*      curs  = (int*)alloc((size_t)N * 4);
    int*      esrc  = (int*)alloc((size_t)E * 4);
    int*      edst  = (int*)alloc((size_t)E * 4);
    uint16_t* Qb    = (uint16_t*)alloc((size_t)N * 256 * 2);                   // 25.6 MB
    float*    Gs    = (float*)alloc((size_t)N * 256 * 4);                      // 51.2 MB
    uint32_t* agg   = (uint32_t*)alloc((size_t)N * 256 * 4);                   // 51.2 MB
    uint16_t* xb    = (uint16_t*)alloc((size_t)N * 256 * 2);                   // 25.6 MB
    uint16_t* h     = xb;               // alias: xb dead after layer-1 node GEMM
    uint16_t* d1    = (uint16_t*)Gs;    // alias: Gs dead after layer-2 edge pass

    uint16_t* posb = arena + POS_OFF;
    uint16_t* w1a = arena + W1A_OFF, * w2a = arena + W2A_OFF;
    uint16_t* w1b = arena + W1B_OFF, * w2b = arena + W2B_OFF;
    uint16_t* wd1 = arena + WD1_OFF, * wd2 = arena + WD2_OFF;
    uint16_t* b1a = arena + B1A_OFF, * b1b = arena + B1B_OFF;
    uint16_t* b2a = arena + B2A_OFF, * b2b = arena + B2B_OFF;
    uint16_t* bd1 = arena + BD1_OFF, * bd2 = arena + BD2_OFF;

    int n4      = N * 64;
    int nbElem  = (n4 + 255) / 256;
    int nbNode  = (N + 63) / 64;
    int nbEdge  = (E + 63) / 64;
    int nbE256  = (E + 255) / 256;
    int nbPos   = (N + 7) / 8;

    // ---- detection + canonicalization ----
    detect_fmt<<<1, 64, 0, stream>>>((const uint32_t*)x_raw, (const uint32_t*)ei_raw, flags);
    convert_big<<<(N * 256 / 4 + 255) / 256, 256, 0, stream>>>(x_raw, xb, N * 256, flags);

    ConvArgs ca;
    ca.src[0] = pos_raw;  ca.dstOff[0] = POS_OFF; ca.n[0] = (uint32_t)(N * 3);
    ca.src[1] = d_in[3];  ca.dstOff[1] = W1A_OFF; ca.n[1] = 66304;
    ca.src[2] = d_in[7];  ca.dstOff[2] = W2A_OFF; ca.n[2] = 66304;
    ca.src[3] = d_in[5];  ca.dstOff[3] = W1B_OFF; ca.n[3] = 65536;
    ca.src[4] = d_in[9];  ca.dstOff[4] = W2B_OFF; ca.n[4] = 65536;
    ca.src[5] = d_in[11]; ca.dstOff[5] = WD1_OFF; ca.n[5] = 65536;
    ca.src[6] = d_in[13]; ca.dstOff[6] = WD2_OFF; ca.n[6] = 65536;
    ca.src[7] = d_in[4];  ca.dstOff[7] = B1A_OFF; ca.n[7] = 256;
    ca.src[8] = d_in[6];  ca.dstOff[8] = B1B_OFF; ca.n[8] = 256;
    ca.src[9] = d_in[8];  ca.dstOff[9] = B2A_OFF; ca.n[9] = 256;
    ca.src[10] = d_in[10]; ca.dstOff[10] = B2B_OFF; ca.n[10] = 256;
    ca.src[11] = d_in[12]; ca.dstOff[11] = BD1_OFF; ca.n[11] = 256;
    ca.src[12] = d_in[14]; ca.dstOff[12] = BD2_OFF; ca.n[12] = 256;
    {
        uint32_t maxn = (uint32_t)(N * 3);
        dim3 g((maxn + 255) / 256, 13);
        convert_small<<<g, 256, 0, stream>>>(ca, arena, flags);
    }

    // ---- counting sort of edges by dst (once, reused by both layers) ----
    zero_i32<<<(N + 255) / 256, 256, 0, stream>>>(hist, N);
    hist_dst<<<nbE256, 256, 0, stream>>>(ei_raw, E, hist, flags);
    scan_bins<<<1, 1024, 0, stream>>>(hist, curs, N);
    scatter_edges<<<nbE256, 256, 0, stream>>>(ei_raw, E, curs, esrc, edst, flags);

    transpose_w<<<dim3(256, 6), 256, 0, stream>>>(w1a, w1b, w2a, w2b, wd1, wd2, WT);

    // ---- layer 1 ----
    pos_proj<<<nbPos, 256, 0, stream>>>(posb, w1a + 65536, Qb, N);
    gemm_node<0><<<nbNode, 256, 0, stream>>>(xb, WT + 0 * 65536, b1a, Qb, Gs, N, flags);
    init_agg<<<nbElem, 256, 0, stream>>>(agg, n4);
    edge_gemm_agg<<<nbEdge, 256, 0, stream>>>(Gs, Qb, WT + 1 * 65536, b1b, esrc, edst, E, agg);
    finalize_h<<<nbElem, 256, 0, stream>>>(agg, h, n4);

    // ---- layer 2 ----
    pos_proj<<<nbPos, 256, 0, stream>>>(posb, w2a + 65536, Qb, N);
    gemm_node<0><<<nbNode, 256, 0, stream>>>(h, WT + 2 * 65536, b2a, Qb, Gs, N, flags);
    init_agg<<<nbElem, 256, 0, stream>>>(agg, n4);
    edge_gemm_agg<<<nbEdge, 256, 0, stream>>>(Gs, Qb, WT + 3 * 65536, b2b, esrc, edst, E, agg);
    finalize_h<<<nbElem, 256, 0, stream>>>(agg, h, n4);

    // ---- decoder ----
    gemm_node<1><<<nbNode, 256, 0, stream>>>(h, WT + 4 * 65536, bd1, nullptr, d1, N, flags);
    gemm_node<2><<<nbNode, 256, 0, stream>>>(d1, WT + 5 * 65536, bd2, nullptr, d_out, N, flags);
}